// Round 3
// baseline (1308.407 us; speedup 1.0000x reference)
//
#include <hip/hip_runtime.h>
#include <cstdint>
#include <cstddef>

// Problem constants: B=32, L=2048, D=1024, E=2048
#define B_ 32
#define L_ 2048
#define D_ 1024
#define E_ 2048
// GEMM view: M = B*L = 65536 rows (b,l), N = D = 1024, K = E = 2048

typedef __attribute__((ext_vector_type(8))) short short8;
typedef __attribute__((ext_vector_type(16))) float f32x16;
typedef __attribute__((ext_vector_type(4))) unsigned int uint4v;

// ---- async global->LDS, 16B per lane; LDS dest = uniform base + lane*16 ----
__device__ __forceinline__ void async_copy16(const void* g, void* l) {
  __builtin_amdgcn_global_load_lds((const __attribute__((address_space(1))) void*)g,
                                   (__attribute__((address_space(3))) void*)l, 16, 0, 0);
}

// pack two fp32 -> bf16x2 (round-half-up: add 0x8000, take hi16)
__device__ __forceinline__ unsigned int pack_bf16_2(float lo, float hi) {
  unsigned int ul = __builtin_bit_cast(unsigned int, lo) + 0x8000u;
  unsigned int uh = __builtin_bit_cast(unsigned int, hi) + 0x8000u;
  return (ul >> 16) | (uh & 0xFFFF0000u);
}

// single-instruction pack (RNE): compiler can't derive this from bit-twiddle
__device__ __forceinline__ unsigned int cvt_pk_bf16(float lo, float hi) {
  unsigned int r;
  asm("v_cvt_pk_bf16_f32 %0, %1, %2" : "=v"(r) : "v"(lo), "v"(hi));
  return r;
}

__device__ __forceinline__ float fast_tanh(float x) {
  float e = __expf(2.0f * x);
  return 1.0f - 2.0f / (e + 1.0f);
}

// ---------------- kernel 1: s[b][i] = sum_d dec[b][d] * Ws[i][d] ------------
__global__ __launch_bounds__(256) void k_s(const float* __restrict__ dec,
                                           const float* __restrict__ Ws,
                                           float* __restrict__ s) {
  int wid = threadIdx.x >> 6, lane = threadIdx.x & 63;
  int out = blockIdx.x * 4 + wid;            // 0..32767
  int b = out >> 10, i = out & 1023;
  const float* dr = dec + b * D_;
  const float* wr = Ws + (size_t)i * D_;
  float acc = 0.f;
#pragma unroll
  for (int c = 0; c < 4; ++c) {
    int d0 = c * 256 + lane * 4;
    float4 x = *(const float4*)(dr + d0);
    float4 w = *(const float4*)(wr + d0);
    acc += x.x * w.x + x.y * w.y + x.z * w.z + x.w * w.w;
  }
#pragma unroll
  for (int off = 32; off >= 1; off >>= 1) acc += __shfl_xor(acc, off, 64);
  if (lane == 0) s[out] = acc;
}

// ---------------- kernel 2: W_h fp32 -> bf16 (2M elements) ------------------
__global__ __launch_bounds__(256) void k_cvt(const float* __restrict__ src,
                                             unsigned short* __restrict__ dst) {
  size_t i = ((size_t)blockIdx.x * 256 + threadIdx.x) * 8;
  float4 a = *(const float4*)(src + i);
  float4 b = *(const float4*)(src + i + 4);
  uint4v p;
  p.x = pack_bf16_2(a.x, a.y);
  p.y = pack_bf16_2(a.z, a.w);
  p.z = pack_bf16_2(b.x, b.y);
  p.w = pack_bf16_2(b.z, b.w);
  *(uint4v*)(dst + i) = p;
}

// ---------------- kernel 3: fused GEMM + tanh + v-dot -----------------------
// scores[m] = sum_n v[n] * tanh(s[b][n] + sum_k enc[m][k]*Whb[n][k]),  m=(b,l)
// Block tile 128(M)x128(N), BK=64; 256 threads = 4 waves (2M x 2N), each wave
// owns a 64x64 output tile = 2x2 frags of MFMA 32x32x16 bf16.
//
// A path: global fp32 -> regs -> v_cvt_pk_bf16_f32 -> ds_write_b128.
//   Pack happens ONCE per element at stage time (was 2x in-loop, ~2x the VALU
//   of the MFMA loop -> VALUBusy 45% > MfmaUtil 25%). MFMA loop is now pure
//   ds_read_b128 + MFMA.
// B path: gload_lds direct, double-buffered.
// Pipelining with plain __syncthreads: next-iter loads (B glds + A reg loads)
//   issue at the TOP of the compute phase. The only vmem drain is the pack's
//   implicit vmcnt wait at the next iteration top, so both __syncthreads
//   drains are no-ops (queues already empty) and the whole MFMA phase hides
//   HBM latency. No raw barriers / asm waitcnt -> no race surface.
// LDS layout (A and B identical): 64 lines x 256 B (2 rows/line, 16x 16B
//   units), unit xor-swizzled by line&15 -> <=2-way conflicts (free, m136).
__global__ __launch_bounds__(256, 3) void k_gemm(const float* __restrict__ enc,
                                                 const unsigned short* __restrict__ whb,
                                                 const float* __restrict__ sbias,
                                                 const float* __restrict__ vvec,
                                                 float* __restrict__ scores) {
  __shared__ alignas(16) unsigned short As[64 * 128];     // 16 KB bf16, 64 lines x 256B
  __shared__ alignas(16) unsigned short Bs[2][64 * 128];  // 2 x 16 KB bf16

  const int tid = threadIdx.x;
  const int wid = tid >> 6;        // 0..3
  const int lane = tid & 63;
  const int wm = wid >> 1;         // wave row (M)
  const int wn = wid & 1;          // wave col (N)

  // XCD swizzle: all 8 N-tiles of one M-tile share flat%8 -> same XCD L2.
  const int flat = blockIdx.x;
  const int nt = (flat >> 3) & 7;
  const int mt = (flat & 7) | ((flat >> 6) << 3);
  const int m_base = mt * 128, n_base = nt * 128;
  const int b_idx = m_base >> 11;  // 128 | 2048 -> b uniform per block

  // --- A staging: thread -> (row, k-half); 32 consecutive floats per thread ---
  const int sRow = wid * 32 + (lane >> 1);   // 0..127
  const int sHf = lane & 1;                  // k-half (32 floats)
  const float* gA = enc + (size_t)(m_base + sRow) * E_ + sHf * 32;
  const int sLine = sRow >> 1;
  int aWoff[4];                              // byte offsets into As per 16B unit
#pragma unroll
  for (int c2 = 0; c2 < 4; ++c2) {
    int ul = ((sRow & 1) << 3) + sHf * 4 + c2;        // logical unit = k/8 slot
    aWoff[c2] = sLine * 256 + ((ul ^ (sLine & 15)) << 4);
  }

  // --- B staging via gload_lds (global address carries the LDS swizzle) ---
  const int rp = lane >> 4;
  const int u0 = (lane & 15) ^ rp;
  const unsigned short* gB = whb + (size_t)n_base * E_;
  int offB[4], ldsB[4];
#pragma unroll
  for (int it = 0; it < 4; ++it) {
    int ulog = u0 ^ (it << 2);
    offB[it] = (wid * 32 + it * 8 + 2 * rp + (ulog >> 3)) * E_ + (ulog & 7) * 8;
    ldsB[it] = (wid * 16 + it * 4) * 256;   // byte offset of 4-line chunk
  }

  // --- fragment read addressing (A and B share the same swizzle formula) ---
  const int col = lane & 31;
  const int h = lane >> 5;
  int soff[4];                               // bytes within a line
#pragma unroll
  for (int ks = 0; ks < 4; ++ks)
    soff[ks] = ((((col & 1) << 3) + ks * 2 + h) ^ ((col >> 1) & 15)) << 4;
  const char* aBase[2];
#pragma unroll
  for (int mi = 0; mi < 2; ++mi)
    aBase[mi] = (const char*)As + (wm * 32 + mi * 16 + (col >> 1)) * 256;
  const char* bBase[2];
#pragma unroll
  for (int ni = 0; ni < 2; ++ni)
    bBase[ni] = (const char*)Bs + (wn * 32 + ni * 16 + (col >> 1)) * 256;

  f32x16 acc[2][2] = {};
  float4 rAv[8];

  // --- prologue: fill Bs[0] + A regs for kk=0 ---
#pragma unroll
  for (int it = 0; it < 4; ++it)
    async_copy16(gB + offB[it], (char*)Bs + ldsB[it]);
#pragma unroll
  for (int c = 0; c < 8; ++c)
    rAv[c] = *(const float4*)(gA + c * 4);

  int bufOff = 0;  // byte toggle 0 / 16384 into Bs
  for (int kk = 0; kk < E_; kk += 64) {
    // pack A (implicit vmcnt wait -> A regs + this iter's B glds all landed)
    unsigned int w[16];
#pragma unroll
    for (int i = 0; i < 16; ++i) {
      const float* f = (const float*)&rAv[i >> 1];
      w[i] = cvt_pk_bf16(f[(i & 1) * 2], f[(i & 1) * 2 + 1]);
    }
    __syncthreads();   // all waves done reading As/Bs[cur^1]; vm queue empty
#pragma unroll
    for (int c2 = 0; c2 < 4; ++c2) {
      uint4v q;
      q.x = w[c2 * 4 + 0]; q.y = w[c2 * 4 + 1];
      q.z = w[c2 * 4 + 2]; q.w = w[c2 * 4 + 3];
      *(uint4v*)((char*)As + aWoff[c2]) = q;
    }
    __syncthreads();   // As + Bs[cur] visible; drains lgkm only

    // issue next-iter loads NOW -> in flight across the whole MFMA phase
    if (kk + 64 < E_) {
#pragma unroll
      for (int it = 0; it < 4; ++it)
        async_copy16(gB + offB[it] + kk + 64, (char*)Bs + (bufOff ^ 16384) + ldsB[it]);
#pragma unroll
      for (int c = 0; c < 8; ++c)
        rAv[c] = *(const float4*)(gA + kk + 64 + c * 4);
    }

#pragma unroll
    for (int ks = 0; ks < 4; ++ks) {
      short8 bf[2], af[2];
#pragma unroll
      for (int ni = 0; ni < 2; ++ni) bf[ni] = *(const short8*)(bBase[ni] + bufOff + soff[ks]);
#pragma unroll
      for (int mi = 0; mi < 2; ++mi) af[mi] = *(const short8*)(aBase[mi] + soff[ks]);
#pragma unroll
      for (int mi = 0; mi < 2; ++mi)
#pragma unroll
        for (int ni = 0; ni < 2; ++ni)
          acc[mi][ni] = __builtin_amdgcn_mfma_f32_32x32x16_bf16(af[mi], bf[ni], acc[mi][ni], 0, 0, 0);
    }
    bufOff ^= 16384;
  }

  // --- epilogue: partial = sum over this wave's 64 n of v[n]*tanh(s+h) ---
  // 32x32 C/D layout (m74/m101): col = lane&31, row = (reg&3)+8*(reg>>2)+4*(lane>>5)
  float vv[2], sv[2];
#pragma unroll
  for (int ni = 0; ni < 2; ++ni) {
    int n = n_base + wn * 64 + ni * 32 + col;
    vv[ni] = vvec[n];
    sv[ni] = sbias[b_idx * D_ + n];
  }
#pragma unroll
  for (int mi = 0; mi < 2; ++mi) {
#pragma unroll
    for (int reg = 0; reg < 16; ++reg) {
      float sum = 0.f;
#pragma unroll
      for (int ni = 0; ni < 2; ++ni)
        sum += vv[ni] * fast_tanh(sv[ni] + acc[mi][ni][reg]);
      sum += __shfl_xor(sum, 1, 64);
      sum += __shfl_xor(sum, 2, 64);
      sum += __shfl_xor(sum, 4, 64);
      sum += __shfl_xor(sum, 8, 64);
      sum += __shfl_xor(sum, 16, 64);
      if (col == 0)
        atomicAdd(&scores[m_base + wm * 64 + mi * 32 + (reg & 3) + 8 * (reg >> 2) + h * 4], sum);
    }
  }
}

// ---------------- kernel 4: softmax over L per b (in-place) -----------------
__global__ __launch_bounds__(256) void k_softmax(float* __restrict__ sc) {
  int b = blockIdx.x, tid = threadIdx.x;
  int lane = tid & 63, wid = tid >> 6;
  float* row = sc + (size_t)b * L_;
  float vals[8];
  float mx = -1e30f;
#pragma unroll
  for (int j = 0; j < 8; ++j) { vals[j] = row[tid + j * 256]; mx = fmaxf(mx, vals[j]); }
#pragma unroll
  for (int off = 32; off >= 1; off >>= 1) mx = fmaxf(mx, __shfl_xor(mx, off, 64));
  __shared__ float redm[4], reds[4];
  if (lane == 0) redm[wid] = mx;
  __syncthreads();
  mx = fmaxf(fmaxf(redm[0], redm[1]), fmaxf(redm[2], redm[3]));
  float sum = 0.f;
#pragma unroll
  for (int j = 0; j < 8; ++j) { vals[j] = __expf(vals[j] - mx); sum += vals[j]; }
#pragma unroll
  for (int off = 32; off >= 1; off >>= 1) sum += __shfl_xor(sum, off, 64);
  if (lane == 0) reds[wid] = sum;
  __syncthreads();
  sum = reds[0] + reds[1] + reds[2] + reds[3];
  float inv = 1.0f / sum;
#pragma unroll
  for (int j = 0; j < 8; ++j) row[tid + j * 256] = vals[j] * inv;
}

// ---------------- kernel 5: ctx[b][e] = sum_l attn[b][l] * enc[b][l][e] -----
// 2048 blocks (8/CU, full TLP). lc = bx>>1 (32 chunks of 64 rows), eh = E half.
__global__ __launch_bounds__(256) void k_ctx(const float* __restrict__ enc,
                                             const float* __restrict__ attn,
                                             float* __restrict__ ctx) {
  int b = blockIdx.y;
  int lc = blockIdx.x >> 1;        // 0..31, 64 rows each
  int eh = blockIdx.x & 1;         // E half
  int t = threadIdx.x;
  __shared__ float aw[64];
  if (t < 64) aw[t] = attn[(size_t)b * L_ + lc * 64 + t];
  __syncthreads();
  const float* base = enc + ((size_t)b * L_ + (size_t)lc * 64) * E_ + eh * 1024;
  float4 a0 = make_float4(0.f, 0.f, 0.f, 0.f);
#pragma unroll 4
  for (int l = 0; l < 64; ++l) {
    float w = aw[l];
    float4 x0 = *(const float4*)(base + (size_t)l * E_ + t * 4);
    a0.x += w * x0.x; a0.y += w * x0.y; a0.z += w * x0.z; a0.w += w * x0.w;
  }
  float* cb = ctx + (size_t)b * E_ + eh * 1024 + t * 4;
  atomicAdd(cb + 0, a0.x);
  atomicAdd(cb + 1, a0.y);
  atomicAdd(cb + 2, a0.z);
  atomicAdd(cb + 3, a0.w);
}

extern "C" void kernel_launch(void* const* d_in, const int* in_sizes, int n_in,
                              void* d_out, int out_size, void* d_ws, size_t ws_size,
                              hipStream_t stream) {
  const float* dec = (const float*)d_in[0];  // [32,1024]
  const float* enc = (const float*)d_in[1];  // [32,2048,2048]
  const float* Ws  = (const float*)d_in[2];  // [1024,1024]
  const float* Wh  = (const float*)d_in[3];  // [1024,2048]
  const float* v   = (const float*)d_in[4];  // [1024]

  float* ctx  = (float*)d_out;                   // [32,2048]
  float* attn = (float*)d_out + B_ * E_;         // [32,2048]; also scores scratch

  // workspace: W_h in bf16 (4 MB) + s (128 KB)
  unsigned short* whb = (unsigned short*)d_ws;
  float* sbuf = (float*)((char*)d_ws + (size_t)D_ * E_ * sizeof(unsigned short));

  // zero ctx + scores (both accumulated via atomics)
  hipMemsetAsync(d_out, 0, (size_t)out_size * sizeof(float), stream);

  k_s<<<dim3((B_ * D_) / 4), dim3(256), 0, stream>>>(dec, Ws, sbuf);
  k_cvt<<<dim3((D_ * E_) / (256 * 8)), dim3(256), 0, stream>>>(Wh, whb);
  k_gemm<<<dim3((B_ * L_ / 128) * (D_ / 128)), dim3(256), 0, stream>>>(enc, whb, sbuf, v, attn);
  k_softmax<<<dim3(B_), dim3(256), 0, stream>>>(attn);
  k_ctx<<<dim3(64, B_), dim3(256), 0, stream>>>(enc, attn, ctx);
}

// Round 4
// 1090.087 us; speedup vs baseline: 1.2003x; 1.2003x over previous
//
#include <hip/hip_runtime.h>
#include <cstdint>
#include <cstddef>

// Problem constants: B=32, L=2048, D=1024, E=2048
#define B_ 32
#define L_ 2048
#define D_ 1024
#define E_ 2048
// GEMM view: M = B*L = 65536 rows (b,l), N = D = 1024, K = E = 2048

typedef __attribute__((ext_vector_type(8))) short short8;
typedef __attribute__((ext_vector_type(16))) float f32x16;
typedef __attribute__((ext_vector_type(4))) unsigned int uint4v;

// ---- async global->LDS, 16B per lane; LDS dest = uniform base + lane*16 ----
__device__ __forceinline__ void async_copy16(const void* g, void* l) {
  __builtin_amdgcn_global_load_lds((const __attribute__((address_space(1))) void*)g,
                                   (__attribute__((address_space(3))) void*)l, 16, 0, 0);
}

// pack two fp32 -> bf16x2 (round-half-up: add 0x8000, take hi16)
__device__ __forceinline__ unsigned int pack_bf16_2(float lo, float hi) {
  unsigned int ul = __builtin_bit_cast(unsigned int, lo) + 0x8000u;
  unsigned int uh = __builtin_bit_cast(unsigned int, hi) + 0x8000u;
  return (ul >> 16) | (uh & 0xFFFF0000u);
}

// single-instruction pack (RNE): compiler can't derive this from bit-twiddle
__device__ __forceinline__ unsigned int cvt_pk_bf16(float lo, float hi) {
  unsigned int r;
  asm("v_cvt_pk_bf16_f32 %0, %1, %2" : "=v"(r) : "v"(lo), "v"(hi));
  return r;
}

__device__ __forceinline__ float fast_tanh(float x) {
  float e = __expf(2.0f * x);
  return 1.0f - 2.0f / (e + 1.0f);
}

// ---------------- kernel 1: s[b][i] = sum_d dec[b][d] * Ws[i][d] ------------
__global__ __launch_bounds__(256) void k_s(const float* __restrict__ dec,
                                           const float* __restrict__ Ws,
                                           float* __restrict__ s) {
  int wid = threadIdx.x >> 6, lane = threadIdx.x & 63;
  int out = blockIdx.x * 4 + wid;            // 0..32767
  int b = out >> 10, i = out & 1023;
  const float* dr = dec + b * D_;
  const float* wr = Ws + (size_t)i * D_;
  float acc = 0.f;
#pragma unroll
  for (int c = 0; c < 4; ++c) {
    int d0 = c * 256 + lane * 4;
    float4 x = *(const float4*)(dr + d0);
    float4 w = *(const float4*)(wr + d0);
    acc += x.x * w.x + x.y * w.y + x.z * w.z + x.w * w.w;
  }
#pragma unroll
  for (int off = 32; off >= 1; off >>= 1) acc += __shfl_xor(acc, off, 64);
  if (lane == 0) s[out] = acc;
}

// ---------------- kernel 2: W_h fp32 -> bf16 (2M elements) ------------------
__global__ __launch_bounds__(256) void k_cvt(const float* __restrict__ src,
                                             unsigned short* __restrict__ dst) {
  size_t i = ((size_t)blockIdx.x * 256 + threadIdx.x) * 8;
  float4 a = *(const float4*)(src + i);
  float4 b = *(const float4*)(src + i + 4);
  uint4v p;
  p.x = pack_bf16_2(a.x, a.y);
  p.y = pack_bf16_2(a.z, a.w);
  p.z = pack_bf16_2(b.x, b.y);
  p.w = pack_bf16_2(b.z, b.w);
  *(uint4v*)(dst + i) = p;
}

// ---------------- kernel 3: fused GEMM + tanh + v-dot -----------------------
// scores[m] = sum_n v[n] * tanh(s[b][n] + sum_k enc[m][k]*Whb[n][k]),  m=(b,l)
// Block tile 128(M)x128(N), BK=64; 256 threads = 4 waves (2M x 2N), each wave
// owns a 64x64 output tile = 2x2 frags of MFMA 32x32x16 bf16.
//
// A path: global fp32 -> regs (COALESCED granule mapping) -> v_cvt_pk_bf16_f32
//   -> ds_write_b64. R3's mapping (32 contiguous floats/thread) made each
//   wave-load touch 64 cachelines with 4x redundancy -> L1-request-rate bound
//   (MfmaUtil 17, VALUBusy 14, both idle). New mapping: instr i = 4 consecutive
//   rows, lane=(row-in-quad, 16B granule) -> 16 lanes span 256 contiguous B =
//   16 cachelines/instr, no redundancy. Pack is per-granule so the assignment
//   is free; each granule -> 8 B bf16 -> b64 write at its swizzled slot
//   (32-lane line-group covers all 16 units once -> conflict-free).
// B path: gload_lds direct, double-buffered.
// Pipelining with plain __syncthreads: next-iter loads (B glds + A reg loads)
//   issue at the TOP of the compute phase; the only vmem drain is the pack's
//   implicit vmcnt wait at the next iteration top.
// LDS layout (A and B identical): 64 lines x 256 B (2 rows/line, 16x 16B
//   units), unit xor-swizzled by line&15. Identical logical layout to R3
//   (correctness-verified); only the writer granularity changed.
__global__ __launch_bounds__(256, 3) void k_gemm(const float* __restrict__ enc,
                                                 const unsigned short* __restrict__ whb,
                                                 const float* __restrict__ sbias,
                                                 const float* __restrict__ vvec,
                                                 float* __restrict__ scores) {
  __shared__ alignas(16) unsigned short As[64 * 128];     // 16 KB bf16, 64 lines x 256B
  __shared__ alignas(16) unsigned short Bs[2][64 * 128];  // 2 x 16 KB bf16

  const int tid = threadIdx.x;
  const int wid = tid >> 6;        // 0..3
  const int lane = tid & 63;
  const int wm = wid >> 1;         // wave row (M)
  const int wn = wid & 1;          // wave col (N)

  // XCD swizzle: all 8 N-tiles of one M-tile share flat%8 -> same XCD L2.
  const int flat = blockIdx.x;
  const int nt = (flat >> 3) & 7;
  const int mt = (flat & 7) | ((flat >> 6) << 3);
  const int m_base = mt * 128, n_base = nt * 128;
  const int b_idx = m_base >> 11;  // 128 | 2048 -> b uniform per block

  // --- A staging: coalesced granule mapping ---
  // instr i: rows R0 = wid*32 + i*4 .. +3; lane -> row R0 + (lane>>4),
  // granule g = lane&15 (4 floats at k = g*4). 16 lanes = 256 B contiguous.
  const int aRow = lane >> 4;      // 0..3 row-in-quad
  const int aG = lane & 15;        // fp32 granule index along k
  const float* gAr = enc + (size_t)(m_base + wid * 32 + aRow) * E_ + aG * 4;
  const int aP = aRow & 1;                 // row parity (constant per thread)
  const int aUl = aP * 8 + (aG >> 1);      // logical 16B unit within line
  const int aBy = (aG & 1) * 8;            // byte offset within unit
  int aWoff[8];
#pragma unroll
  for (int i = 0; i < 8; ++i) {
    int line = wid * 16 + i * 2 + (aRow >> 1);
    aWoff[i] = line * 256 + ((aUl ^ (line & 15)) << 4) + aBy;
  }

  // --- B staging via gload_lds (global address carries the LDS swizzle) ---
  const int rp = lane >> 4;
  const int u0 = (lane & 15) ^ rp;
  const unsigned short* gB = whb + (size_t)n_base * E_;
  int offB[4], ldsB[4];
#pragma unroll
  for (int it = 0; it < 4; ++it) {
    int ulog = u0 ^ (it << 2);
    offB[it] = (wid * 32 + it * 8 + 2 * rp + (ulog >> 3)) * E_ + (ulog & 7) * 8;
    ldsB[it] = (wid * 16 + it * 4) * 256;   // byte offset of 4-line chunk
  }

  // --- fragment read addressing (A and B share the same swizzle formula) ---
  const int col = lane & 31;
  const int h = lane >> 5;
  int soff[4];                               // bytes within a line
#pragma unroll
  for (int ks = 0; ks < 4; ++ks)
    soff[ks] = ((((col & 1) << 3) + ks * 2 + h) ^ ((col >> 1) & 15)) << 4;
  const char* aBase[2];
#pragma unroll
  for (int mi = 0; mi < 2; ++mi)
    aBase[mi] = (const char*)As + (wm * 32 + mi * 16 + (col >> 1)) * 256;
  const char* bBase[2];
#pragma unroll
  for (int ni = 0; ni < 2; ++ni)
    bBase[ni] = (const char*)Bs + (wn * 32 + ni * 16 + (col >> 1)) * 256;

  f32x16 acc[2][2] = {};
  float4 rAv[8];

  // --- prologue: fill Bs[0] + A regs for kk=0 ---
#pragma unroll
  for (int it = 0; it < 4; ++it)
    async_copy16(gB + offB[it], (char*)Bs + ldsB[it]);
#pragma unroll
  for (int i = 0; i < 8; ++i)
    rAv[i] = *(const float4*)(gAr + (size_t)(i * 4) * E_);

  int bufOff = 0;  // byte toggle 0 / 16384 into Bs
  for (int kk = 0; kk < E_; kk += 64) {
    // pack A (implicit vmcnt wait -> A regs + this iter's B glds all landed)
    uint2 qa[8];
#pragma unroll
    for (int i = 0; i < 8; ++i) {
      qa[i].x = cvt_pk_bf16(rAv[i].x, rAv[i].y);
      qa[i].y = cvt_pk_bf16(rAv[i].z, rAv[i].w);
    }
    __syncthreads();   // all waves done reading As/Bs[cur^1]; vm queue empty
#pragma unroll
    for (int i = 0; i < 8; ++i)
      *(uint2*)((char*)As + aWoff[i]) = qa[i];
    __syncthreads();   // As + Bs[cur] visible; drains lgkm only

    // issue next-iter loads NOW -> in flight across the whole MFMA phase
    if (kk + 64 < E_) {
#pragma unroll
      for (int it = 0; it < 4; ++it)
        async_copy16(gB + offB[it] + kk + 64, (char*)Bs + (bufOff ^ 16384) + ldsB[it]);
#pragma unroll
      for (int i = 0; i < 8; ++i)
        rAv[i] = *(const float4*)(gAr + (size_t)(i * 4) * E_ + kk + 64);
    }

#pragma unroll
    for (int ks = 0; ks < 4; ++ks) {
      short8 bf[2], af[2];
#pragma unroll
      for (int ni = 0; ni < 2; ++ni) bf[ni] = *(const short8*)(bBase[ni] + bufOff + soff[ks]);
#pragma unroll
      for (int mi = 0; mi < 2; ++mi) af[mi] = *(const short8*)(aBase[mi] + soff[ks]);
#pragma unroll
      for (int mi = 0; mi < 2; ++mi)
#pragma unroll
        for (int ni = 0; ni < 2; ++ni)
          acc[mi][ni] = __builtin_amdgcn_mfma_f32_32x32x16_bf16(af[mi], bf[ni], acc[mi][ni], 0, 0, 0);
    }
    bufOff ^= 16384;
  }

  // --- epilogue: partial = sum over this wave's 64 n of v[n]*tanh(s+h) ---
  // 32x32 C/D layout (m74/m101): col = lane&31, row = (reg&3)+8*(reg>>2)+4*(lane>>5)
  float vv[2], sv[2];
#pragma unroll
  for (int ni = 0; ni < 2; ++ni) {
    int n = n_base + wn * 64 + ni * 32 + col;
    vv[ni] = vvec[n];
    sv[ni] = sbias[b_idx * D_ + n];
  }
#pragma unroll
  for (int mi = 0; mi < 2; ++mi) {
#pragma unroll
    for (int reg = 0; reg < 16; ++reg) {
      float sum = 0.f;
#pragma unroll
      for (int ni = 0; ni < 2; ++ni)
        sum += vv[ni] * fast_tanh(sv[ni] + acc[mi][ni][reg]);
      sum += __shfl_xor(sum, 1, 64);
      sum += __shfl_xor(sum, 2, 64);
      sum += __shfl_xor(sum, 4, 64);
      sum += __shfl_xor(sum, 8, 64);
      sum += __shfl_xor(sum, 16, 64);
      if (col == 0)
        atomicAdd(&scores[m_base + wm * 64 + mi * 32 + (reg & 3) + 8 * (reg >> 2) + h * 4], sum);
    }
  }
}

// ---------------- kernel 4: softmax over L per b (in-place) -----------------
__global__ __launch_bounds__(256) void k_softmax(float* __restrict__ sc) {
  int b = blockIdx.x, tid = threadIdx.x;
  int lane = tid & 63, wid = tid >> 6;
  float* row = sc + (size_t)b * L_;
  float vals[8];
  float mx = -1e30f;
#pragma unroll
  for (int j = 0; j < 8; ++j) { vals[j] = row[tid + j * 256]; mx = fmaxf(mx, vals[j]); }
#pragma unroll
  for (int off = 32; off >= 1; off >>= 1) mx = fmaxf(mx, __shfl_xor(mx, off, 64));
  __shared__ float redm[4], reds[4];
  if (lane == 0) redm[wid] = mx;
  __syncthreads();
  mx = fmaxf(fmaxf(redm[0], redm[1]), fmaxf(redm[2], redm[3]));
  float sum = 0.f;
#pragma unroll
  for (int j = 0; j < 8; ++j) { vals[j] = __expf(vals[j] - mx); sum += vals[j]; }
#pragma unroll
  for (int off = 32; off >= 1; off >>= 1) sum += __shfl_xor(sum, off, 64);
  if (lane == 0) reds[wid] = sum;
  __syncthreads();
  sum = reds[0] + reds[1] + reds[2] + reds[3];
  float inv = 1.0f / sum;
#pragma unroll
  for (int j = 0; j < 8; ++j) row[tid + j * 256] = vals[j] * inv;
}

// ---------------- kernel 5: ctx[b][e] = sum_l attn[b][l] * enc[b][l][e] -----
// 2048 blocks (8/CU, full TLP). lc = bx>>1 (32 chunks of 64 rows), eh = E half.
// (unchanged as a control: "rest" time has been invariant across k_ctx shapes)
__global__ __launch_bounds__(256) void k_ctx(const float* __restrict__ enc,
                                             const float* __restrict__ attn,
                                             float* __restrict__ ctx) {
  int b = blockIdx.y;
  int lc = blockIdx.x >> 1;        // 0..31, 64 rows each
  int eh = blockIdx.x & 1;         // E half
  int t = threadIdx.x;
  __shared__ float aw[64];
  if (t < 64) aw[t] = attn[(size_t)b * L_ + lc * 64 + t];
  __syncthreads();
  const float* base = enc + ((size_t)b * L_ + (size_t)lc * 64) * E_ + eh * 1024;
  float4 a0 = make_float4(0.f, 0.f, 0.f, 0.f);
#pragma unroll 4
  for (int l = 0; l < 64; ++l) {
    float w = aw[l];
    float4 x0 = *(const float4*)(base + (size_t)l * E_ + t * 4);
    a0.x += w * x0.x; a0.y += w * x0.y; a0.z += w * x0.z; a0.w += w * x0.w;
  }
  float* cb = ctx + (size_t)b * E_ + eh * 1024 + t * 4;
  atomicAdd(cb + 0, a0.x);
  atomicAdd(cb + 1, a0.y);
  atomicAdd(cb + 2, a0.z);
  atomicAdd(cb + 3, a0.w);
}

extern "C" void kernel_launch(void* const* d_in, const int* in_sizes, int n_in,
                              void* d_out, int out_size, void* d_ws, size_t ws_size,
                              hipStream_t stream) {
  const float* dec = (const float*)d_in[0];  // [32,1024]
  const float* enc = (const float*)d_in[1];  // [32,2048,2048]
  const float* Ws  = (const float*)d_in[2];  // [1024,1024]
  const float* Wh  = (const float*)d_in[3];  // [1024,2048]
  const float* v   = (const float*)d_in[4];  // [1024]

  float* ctx  = (float*)d_out;                   // [32,2048]
  float* attn = (float*)d_out + B_ * E_;         // [32,2048]; also scores scratch

  // workspace: W_h in bf16 (4 MB) + s (128 KB)
  unsigned short* whb = (unsigned short*)d_ws;
  float* sbuf = (float*)((char*)d_ws + (size_t)D_ * E_ * sizeof(unsigned short));

  // zero ctx + scores (both accumulated via atomics)
  hipMemsetAsync(d_out, 0, (size_t)out_size * sizeof(float), stream);

  k_s<<<dim3((B_ * D_) / 4), dim3(256), 0, stream>>>(dec, Ws, sbuf);
  k_cvt<<<dim3((D_ * E_) / (256 * 8)), dim3(256), 0, stream>>>(Wh, whb);
  k_gemm<<<dim3((B_ * L_ / 128) * (D_ / 128)), dim3(256), 0, stream>>>(enc, whb, sbuf, v, attn);
  k_softmax<<<dim3(B_), dim3(256), 0, stream>>>(attn);
  k_ctx<<<dim3(64, B_), dim3(256), 0, stream>>>(enc, attn, ctx);
}

// Round 5
// 1069.278 us; speedup vs baseline: 1.2236x; 1.0195x over previous
//
#include <hip/hip_runtime.h>
#include <cstdint>
#include <cstddef>

// Problem constants: B=32, L=2048, D=1024, E=2048
#define B_ 32
#define L_ 2048
#define D_ 1024
#define E_ 2048
// GEMM view: M = B*L = 65536 rows (b,l), N = D = 1024, K = E = 2048

typedef __attribute__((ext_vector_type(8))) short short8;
typedef __attribute__((ext_vector_type(16))) float f32x16;
typedef __attribute__((ext_vector_type(4))) unsigned int uint4v;

// pack two fp32 -> bf16x2 (round-half-up: add 0x8000, take hi16)
__device__ __forceinline__ unsigned int pack_bf16_2(float lo, float hi) {
  unsigned int ul = __builtin_bit_cast(unsigned int, lo) + 0x8000u;
  unsigned int uh = __builtin_bit_cast(unsigned int, hi) + 0x8000u;
  return (ul >> 16) | (uh & 0xFFFF0000u);
}

// single-instruction pack (RNE): compiler can't derive this from bit-twiddle
__device__ __forceinline__ unsigned int cvt_pk_bf16(float lo, float hi) {
  unsigned int r;
  asm("v_cvt_pk_bf16_f32 %0, %1, %2" : "=v"(r) : "v"(lo), "v"(hi));
  return r;
}

__device__ __forceinline__ float fast_tanh(float x) {
  float e = __expf(2.0f * x);
  return 1.0f - 2.0f / (e + 1.0f);
}

// ---------------- kernel 1: s[b][i] = sum_d dec[b][d] * Ws[i][d] ------------
__global__ __launch_bounds__(256) void k_s(const float* __restrict__ dec,
                                           const float* __restrict__ Ws,
                                           float* __restrict__ s) {
  int wid = threadIdx.x >> 6, lane = threadIdx.x & 63;
  int out = blockIdx.x * 4 + wid;            // 0..32767
  int b = out >> 10, i = out & 1023;
  const float* dr = dec + b * D_;
  const float* wr = Ws + (size_t)i * D_;
  float acc = 0.f;
#pragma unroll
  for (int c = 0; c < 4; ++c) {
    int d0 = c * 256 + lane * 4;
    float4 x = *(const float4*)(dr + d0);
    float4 w = *(const float4*)(wr + d0);
    acc += x.x * w.x + x.y * w.y + x.z * w.z + x.w * w.w;
  }
#pragma unroll
  for (int off = 32; off >= 1; off >>= 1) acc += __shfl_xor(acc, off, 64);
  if (lane == 0) s[out] = acc;
}

// ---------------- kernel 2: W_h fp32 -> bf16 (2M elements) ------------------
__global__ __launch_bounds__(256) void k_cvt(const float* __restrict__ src,
                                             unsigned short* __restrict__ dst) {
  size_t i = ((size_t)blockIdx.x * 256 + threadIdx.x) * 8;
  float4 a = *(const float4*)(src + i);
  float4 b = *(const float4*)(src + i + 4);
  uint4v p;
  p.x = pack_bf16_2(a.x, a.y);
  p.y = pack_bf16_2(a.z, a.w);
  p.z = pack_bf16_2(b.x, b.y);
  p.w = pack_bf16_2(b.z, b.w);
  *(uint4v*)(dst + i) = p;
}

// ---------------- kernel 3: fused GEMM + tanh + v-dot -----------------------
// scores[m] = sum_n v[n] * tanh(s[b][n] + sum_k enc[m][k]*Whb[n][k]),  m=(b,l)
// Block tile 128(M)x128(N), BK=64; 256 threads = 4 waves (2M x 2N).
//
// R4 was latency-bound (MfmaUtil 26 / VALUBusy 24 / HBM 13 -- all idle):
// prefetch window = 1 MFMA phase (~400cy) < HBM latency (~900cy), and
// __syncthreads() full-drains vmcnt (m97), capping pipeline depth at 1.
// This round (T3/T4 regime, plain-HIP m201 skeleton):
//  - ALL staging via registers (B: global->reg->ds_write_b128, same LDS bytes
//    as R4's gload_lds). No gload_lds anywhere -> the compiler's precise
//    counted vmcnt(N) manages the pipeline; raw s_barrier never drains vmem.
//  - Raw s_barrier x2 per K-step; publish via asm lgkmcnt(0)+sched_barrier(0)
//    (rule 18). Every ds_read is consumed by an in-phase MFMA, so lgkm waits
//    complete before barrier #1 -> no read/write overlap hazard.
//  - A prefetch distance 2 (two reg sets, loop unrolled x2 for static reg
//    indexing, rule 20); B distance 1 (whb is L2-resident). Steady state:
//    pack(kk) waits vmcnt leaving B(kk)+A(kk+64) in flight; B-write waits
//    leaving A(kk+64) in flight ~2 iterations => covers HBM latency.
//  - LDS single-buffered 32 KB (barrier #1 separates reads from rewrite).
// Layouts/swizzles identical to R4 (verified): 64 lines x 256 B, 16B units
// xor-swizzled by line&15; A granule map per R4.
__global__ __launch_bounds__(256, 2) void k_gemm(const float* __restrict__ enc,
                                                 const unsigned short* __restrict__ whb,
                                                 const float* __restrict__ sbias,
                                                 const float* __restrict__ vvec,
                                                 float* __restrict__ scores) {
  __shared__ alignas(16) unsigned short As[64 * 128];  // 16 KB bf16
  __shared__ alignas(16) unsigned short Bs[64 * 128];  // 16 KB bf16

  const int tid = threadIdx.x;
  const int wid = tid >> 6;        // 0..3
  const int lane = tid & 63;
  const int wm = wid >> 1;         // wave row (M)
  const int wn = wid & 1;          // wave col (N)

  // XCD swizzle: all 8 N-tiles of one M-tile share flat%8 -> same XCD L2.
  const int flat = blockIdx.x;
  const int nt = (flat >> 3) & 7;
  const int mt = (flat & 7) | ((flat >> 6) << 3);
  const int m_base = mt * 128, n_base = nt * 128;
  const int b_idx = m_base >> 11;  // 128 | 2048 -> b uniform per block

  // --- A staging: coalesced granule mapping (R4, verified) ---
  const int aRow = lane >> 4;      // 0..3 row-in-quad
  const int aG = lane & 15;        // fp32 granule index along k
  const float* gAr = enc + (size_t)(m_base + wid * 32 + aRow) * E_ + aG * 4;
  const int aUl = (aRow & 1) * 8 + (aG >> 1);
  const int aBy = (aG & 1) * 8;
  int aWoff[8];
#pragma unroll
  for (int i = 0; i < 8; ++i) {
    int line = wid * 16 + i * 2 + (aRow >> 1);
    aWoff[i] = line * 256 + ((aUl ^ (line & 15)) << 4) + aBy;
  }

  // --- B staging (R4's global/LDS mapping, now via regs) ---
  const int rp = lane >> 4;
  const int u0 = (lane & 15) ^ rp;
  const unsigned short* gB = whb + (size_t)n_base * E_;
  int offB[4], ldsB[4];
#pragma unroll
  for (int it = 0; it < 4; ++it) {
    int ulog = u0 ^ (it << 2);
    offB[it] = (wid * 32 + it * 8 + 2 * rp + (ulog >> 3)) * E_ + (ulog & 7) * 8;
    ldsB[it] = (wid * 16 + it * 4) * 256 + lane * 16;  // byte dest (linear)
  }

  // --- fragment read addressing (R4, verified) ---
  const int col = lane & 31;
  const int h = lane >> 5;
  int soff[4];
#pragma unroll
  for (int ks = 0; ks < 4; ++ks)
    soff[ks] = ((((col & 1) << 3) + ks * 2 + h) ^ ((col >> 1) & 15)) << 4;
  const char* aBase[2];
#pragma unroll
  for (int mi = 0; mi < 2; ++mi)
    aBase[mi] = (const char*)As + (wm * 32 + mi * 16 + (col >> 1)) * 256;
  const char* bBase[2];
#pragma unroll
  for (int ni = 0; ni < 2; ++ni)
    bBase[ni] = (const char*)Bs + (wn * 32 + ni * 16 + (col >> 1)) * 256;

  f32x16 acc[2][2] = {};
  float4 rAv0[8], rAv1[8];   // A prefetch sets (distance 2)
  uint4v rBv[4];             // B prefetch set (distance 1)

  // --- prologue: issue B(0), A(0)->set0, A(64)->set1 (queue order matters) ---
#pragma unroll
  for (int it = 0; it < 4; ++it)
    rBv[it] = *(const uint4v*)(gB + offB[it]);
#pragma unroll
  for (int i = 0; i < 8; ++i)
    rAv0[i] = *(const float4*)(gAr + (size_t)(i * 4) * E_);
#pragma unroll
  for (int i = 0; i < 8; ++i)
    rAv1[i] = *(const float4*)(gAr + (size_t)(i * 4) * E_ + 64);

  // One K-step phase. Compiler inserts counted vmcnt for RA/rBv uses;
  // raw barriers never drain vmem -> issued loads stay in flight across them.
#define GPHASE(KK, RA, DO_B, DO_A)                                          \
  {                                                                         \
    uint2 qa[8];                                                            \
    _Pragma("unroll") for (int i = 0; i < 8; ++i) {                         \
      qa[i].x = cvt_pk_bf16(RA[i].x, RA[i].y);                              \
      qa[i].y = cvt_pk_bf16(RA[i].z, RA[i].w);                              \
    }                                                                       \
    __builtin_amdgcn_sched_barrier(0);                                      \
    __builtin_amdgcn_s_barrier(); /* #1: prev MFMA reads consumed */        \
    __builtin_amdgcn_sched_barrier(0);                                      \
    _Pragma("unroll") for (int i = 0; i < 8; ++i)                           \
      *(uint2*)((char*)As + aWoff[i]) = qa[i];                              \
    _Pragma("unroll") for (int it = 0; it < 4; ++it)                        \
      *(uint4v*)((char*)Bs + ldsB[it]) = rBv[it];                           \
    if (DO_B) {                                                             \
      _Pragma("unroll") for (int it = 0; it < 4; ++it)                      \
        rBv[it] = *(const uint4v*)(gB + offB[it] + (KK) + 64);              \
    }                                                                       \
    if (DO_A) {                                                             \
      _Pragma("unroll") for (int i = 0; i < 8; ++i)                         \
        RA[i] = *(const float4*)(gAr + (size_t)(i * 4) * E_ + (KK) + 128);  \
    }                                                                       \
    asm volatile("s_waitcnt lgkmcnt(0)" ::: "memory");                      \
    __builtin_amdgcn_sched_barrier(0);                                      \
    __builtin_amdgcn_s_barrier(); /* #2: LDS published */                   \
    __builtin_amdgcn_sched_barrier(0);                                      \
    _Pragma("unroll") for (int ks = 0; ks < 4; ++ks) {                      \
      short8 bf[2], af[2];                                                  \
      _Pragma("unroll") for (int ni = 0; ni < 2; ++ni)                      \
        bf[ni] = *(const short8*)(bBase[ni] + soff[ks]);                    \
      _Pragma("unroll") for (int mi = 0; mi < 2; ++mi)                      \
        af[mi] = *(const short8*)(aBase[mi] + soff[ks]);                    \
      _Pragma("unroll") for (int mi = 0; mi < 2; ++mi)                      \
        _Pragma("unroll") for (int ni = 0; ni < 2; ++ni)                    \
          acc[mi][ni] = __builtin_amdgcn_mfma_f32_32x32x16_bf16(            \
              af[mi], bf[ni], acc[mi][ni], 0, 0, 0);                        \
    }                                                                       \
  }

  // main loop: 15 double-steps fully pipelined, then peeled tail (no issue)
  for (int kk = 0; kk < 1920; kk += 128) {
    GPHASE(kk, rAv0, true, true);
    GPHASE(kk + 64, rAv1, true, true);
  }
  GPHASE(1920, rAv0, true, false);   // issues B(1984) only
  GPHASE(1984, rAv1, false, false);  // drains
#undef GPHASE

  // --- epilogue: partial = sum over this wave's 64 n of v[n]*tanh(s+h) ---
  // 32x32 C/D layout (m74/m101): col = lane&31, row = (reg&3)+8*(reg>>2)+4*(lane>>5)
  float vv[2], sv[2];
#pragma unroll
  for (int ni = 0; ni < 2; ++ni) {
    int n = n_base + wn * 64 + ni * 32 + col;
    vv[ni] = vvec[n];
    sv[ni] = sbias[b_idx * D_ + n];
  }
#pragma unroll
  for (int mi = 0; mi < 2; ++mi) {
#pragma unroll
    for (int reg = 0; reg < 16; ++reg) {
      float sum = 0.f;
#pragma unroll
      for (int ni = 0; ni < 2; ++ni)
        sum += vv[ni] * fast_tanh(sv[ni] + acc[mi][ni][reg]);
      sum += __shfl_xor(sum, 1, 64);
      sum += __shfl_xor(sum, 2, 64);
      sum += __shfl_xor(sum, 4, 64);
      sum += __shfl_xor(sum, 8, 64);
      sum += __shfl_xor(sum, 16, 64);
      if (col == 0)
        atomicAdd(&scores[m_base + wm * 64 + mi * 32 + (reg & 3) + 8 * (reg >> 2) + h * 4], sum);
    }
  }
}

// ---------------- kernel 4: softmax over L per b (in-place) -----------------
__global__ __launch_bounds__(256) void k_softmax(float* __restrict__ sc) {
  int b = blockIdx.x, tid = threadIdx.x;
  int lane = tid & 63, wid = tid >> 6;
  float* row = sc + (size_t)b * L_;
  float vals[8];
  float mx = -1e30f;
#pragma unroll
  for (int j = 0; j < 8; ++j) { vals[j] = row[tid + j * 256]; mx = fmaxf(mx, vals[j]); }
#pragma unroll
  for (int off = 32; off >= 1; off >>= 1) mx = fmaxf(mx, __shfl_xor(mx, off, 64));
  __shared__ float redm[4], reds[4];
  if (lane == 0) redm[wid] = mx;
  __syncthreads();
  mx = fmaxf(fmaxf(redm[0], redm[1]), fmaxf(redm[2], redm[3]));
  float sum = 0.f;
#pragma unroll
  for (int j = 0; j < 8; ++j) { vals[j] = __expf(vals[j] - mx); sum += vals[j]; }
#pragma unroll
  for (int off = 32; off >= 1; off >>= 1) sum += __shfl_xor(sum, off, 64);
  if (lane == 0) reds[wid] = sum;
  __syncthreads();
  sum = reds[0] + reds[1] + reds[2] + reds[3];
  float inv = 1.0f / sum;
#pragma unroll
  for (int j = 0; j < 8; ++j) row[tid + j * 256] = vals[j] * inv;
}

// ---------------- kernel 5: ctx[b][e] = sum_l attn[b][l] * enc[b][l][e] -----
// 2048 blocks (8/CU). unroll 8 for deeper MLP.
__global__ __launch_bounds__(256) void k_ctx(const float* __restrict__ enc,
                                             const float* __restrict__ attn,
                                             float* __restrict__ ctx) {
  int b = blockIdx.y;
  int lc = blockIdx.x >> 1;        // 0..31, 64 rows each
  int eh = blockIdx.x & 1;         // E half
  int t = threadIdx.x;
  __shared__ float aw[64];
  if (t < 64) aw[t] = attn[(size_t)b * L_ + lc * 64 + t];
  __syncthreads();
  const float* base = enc + ((size_t)b * L_ + (size_t)lc * 64) * E_ + eh * 1024;
  float4 a0 = make_float4(0.f, 0.f, 0.f, 0.f);
#pragma unroll 8
  for (int l = 0; l < 64; ++l) {
    float w = aw[l];
    float4 x0 = *(const float4*)(base + (size_t)l * E_ + t * 4);
    a0.x += w * x0.x; a0.y += w * x0.y; a0.z += w * x0.z; a0.w += w * x0.w;
  }
  float* cb = ctx + (size_t)b * E_ + eh * 1024 + t * 4;
  atomicAdd(cb + 0, a0.x);
  atomicAdd(cb + 1, a0.y);
  atomicAdd(cb + 2, a0.z);
  atomicAdd(cb + 3, a0.w);
}

extern "C" void kernel_launch(void* const* d_in, const int* in_sizes, int n_in,
                              void* d_out, int out_size, void* d_ws, size_t ws_size,
                              hipStream_t stream) {
  const float* dec = (const float*)d_in[0];  // [32,1024]
  const float* enc = (const float*)d_in[1];  // [32,2048,2048]
  const float* Ws  = (const float*)d_in[2];  // [1024,1024]
  const float* Wh  = (const float*)d_in[3];  // [1024,2048]
  const float* v   = (const float*)d_in[4];  // [1024]

  float* ctx  = (float*)d_out;                   // [32,2048]
  float* attn = (float*)d_out + B_ * E_;         // [32,2048]; also scores scratch

  // workspace: W_h in bf16 (4 MB) + s (128 KB)
  unsigned short* whb = (unsigned short*)d_ws;
  float* sbuf = (float*)((char*)d_ws + (size_t)D_ * E_ * sizeof(unsigned short));

  // zero ctx + scores (both accumulated via atomics)
  hipMemsetAsync(d_out, 0, (size_t)out_size * sizeof(float), stream);

  k_s<<<dim3((B_ * D_) / 4), dim3(256), 0, stream>>>(dec, Ws, sbuf);
  k_cvt<<<dim3((D_ * E_) / (256 * 8)), dim3(256), 0, stream>>>(Wh, whb);
  k_gemm<<<dim3((B_ * L_ / 128) * (D_ / 128)), dim3(256), 0, stream>>>(enc, whb, sbuf, v, attn);
  k_softmax<<<dim3(B_), dim3(256), 0, stream>>>(attn);
  k_ctx<<<dim3(64, B_), dim3(256), 0, stream>>>(enc, attn, ctx);
}

// Round 6
// 1064.572 us; speedup vs baseline: 1.2290x; 1.0044x over previous
//
#include <hip/hip_runtime.h>
#include <cstdint>
#include <cstddef>

// Problem constants: B=32, L=2048, D=1024, E=2048
#define B_ 32
#define L_ 2048
#define D_ 1024
#define E_ 2048
// GEMM view: M = B*L = 65536 rows (b,l), N = D = 1024, K = E = 2048

typedef __attribute__((ext_vector_type(8))) short short8;
typedef __attribute__((ext_vector_type(16))) float f32x16;
typedef __attribute__((ext_vector_type(4))) unsigned int uint4v;

// pack two fp32 -> bf16x2 (round-half-up: add 0x8000, take hi16)
__device__ __forceinline__ unsigned int pack_bf16_2(float lo, float hi) {
  unsigned int ul = __builtin_bit_cast(unsigned int, lo) + 0x8000u;
  unsigned int uh = __builtin_bit_cast(unsigned int, hi) + 0x8000u;
  return (ul >> 16) | (uh & 0xFFFF0000u);
}

// single-instruction pack (RNE)
__device__ __forceinline__ unsigned int cvt_pk_bf16(float lo, float hi) {
  unsigned int r;
  asm("v_cvt_pk_bf16_f32 %0, %1, %2" : "=v"(r) : "v"(lo), "v"(hi));
  return r;
}

__device__ __forceinline__ float fast_tanh(float x) {
  float e = __expf(2.0f * x);
  return 1.0f - 2.0f / (e + 1.0f);
}

// ---------------- kernel 1: s[b][i] = sum_d dec[b][d] * Ws[i][d] ------------
__global__ __launch_bounds__(256) void k_s(const float* __restrict__ dec,
                                           const float* __restrict__ Ws,
                                           float* __restrict__ s) {
  int wid = threadIdx.x >> 6, lane = threadIdx.x & 63;
  int out = blockIdx.x * 4 + wid;            // 0..32767
  int b = out >> 10, i = out & 1023;
  const float* dr = dec + b * D_;
  const float* wr = Ws + (size_t)i * D_;
  float acc = 0.f;
#pragma unroll
  for (int c = 0; c < 4; ++c) {
    int d0 = c * 256 + lane * 4;
    float4 x = *(const float4*)(dr + d0);
    float4 w = *(const float4*)(wr + d0);
    acc += x.x * w.x + x.y * w.y + x.z * w.z + x.w * w.w;
  }
#pragma unroll
  for (int off = 32; off >= 1; off >>= 1) acc += __shfl_xor(acc, off, 64);
  if (lane == 0) s[out] = acc;
}

// ---------------- kernel 2: W_h fp32 -> bf16 (2M elements) ------------------
__global__ __launch_bounds__(256) void k_cvt(const float* __restrict__ src,
                                             unsigned short* __restrict__ dst) {
  size_t i = ((size_t)blockIdx.x * 256 + threadIdx.x) * 8;
  float4 a = *(const float4*)(src + i);
  float4 b = *(const float4*)(src + i + 4);
  uint4v p;
  p.x = pack_bf16_2(a.x, a.y);
  p.y = pack_bf16_2(a.z, a.w);
  p.z = pack_bf16_2(b.x, b.y);
  p.w = pack_bf16_2(b.z, b.w);
  *(uint4v*)(dst + i) = p;
}

// ---------------- kernel 3: fused GEMM + tanh + v-dot -----------------------
// scores[m] = sum_n v[n] * tanh(s[b][n] + sum_k enc[m][k]*Whb[n][k]),  m=(b,l)
// Block tile 128(M)x128(N), BK=64; 256 threads = 4 waves (2M x 2N).
//
// R5 was still lockstep-bound: 2 barriers per K-step, LDS-write phase between
// them (matrix pipe guaranteed idle), 8 waves/CU. This round: DOUBLE-BUFFERED
// LDS (64 KB) + ONE raw s_barrier per K-step. Inside each barrier interval:
//   pack A(t+1) + ds_write buf[nxt]  ||  ds_read buf[cur] + 16 MFMA
// so ds_writes overlap MFMAs across waves and barrier count halves (64->32).
// Loads stay reg-staged with compiler-counted vmcnt; issue order per iter is
// B(t+2) then A(t+3), so pack waits leave [B,A] in flight and the B-write
// wait (older B) leaves A in flight ~2 iterations (~covers HBM latency).
// Safety: lgkmcnt(0)+sched_barrier(0) before each s_barrier (writes published,
// reads retired); reads(cur) and writes(nxt) are disjoint LDS ranges.
// Layouts/swizzles identical to R4/R5 (verified).
__global__ __launch_bounds__(256, 2) void k_gemm(const float* __restrict__ enc,
                                                 const unsigned short* __restrict__ whb,
                                                 const float* __restrict__ sbias,
                                                 const float* __restrict__ vvec,
                                                 float* __restrict__ scores) {
  __shared__ alignas(16) unsigned short As[2][64 * 128];  // 2 x 16 KB bf16
  __shared__ alignas(16) unsigned short Bs[2][64 * 128];  // 2 x 16 KB bf16

  const int tid = threadIdx.x;
  const int wid = tid >> 6;        // 0..3
  const int lane = tid & 63;
  const int wm = wid >> 1;         // wave row (M)
  const int wn = wid & 1;          // wave col (N)

  // XCD swizzle: all 8 N-tiles of one M-tile share flat%8 -> same XCD L2.
  const int flat = blockIdx.x;
  const int nt = (flat >> 3) & 7;
  const int mt = (flat & 7) | ((flat >> 6) << 3);
  const int m_base = mt * 128, n_base = nt * 128;
  const int b_idx = m_base >> 11;  // 128 | 2048 -> b uniform per block

  // --- A staging: coalesced granule mapping (R4, verified) ---
  const int aRow = lane >> 4;      // 0..3 row-in-quad
  const int aG = lane & 15;        // fp32 granule index along k
  const float* gAr = enc + (size_t)(m_base + wid * 32 + aRow) * E_ + aG * 4;
  const int aUl = (aRow & 1) * 8 + (aG >> 1);
  const int aBy = (aG & 1) * 8;
  int aWoff[8];
#pragma unroll
  for (int i = 0; i < 8; ++i) {
    int line = wid * 16 + i * 2 + (aRow >> 1);
    aWoff[i] = line * 256 + ((aUl ^ (line & 15)) << 4) + aBy;
  }

  // --- B staging (R4's global/LDS mapping, reg-staged) ---
  const int rp = lane >> 4;
  const int u0 = (lane & 15) ^ rp;
  const unsigned short* gB = whb + (size_t)n_base * E_;
  int offB[4], ldsB[4];
#pragma unroll
  for (int it = 0; it < 4; ++it) {
    int ulog = u0 ^ (it << 2);
    offB[it] = (wid * 32 + it * 8 + 2 * rp + (ulog >> 3)) * E_ + (ulog & 7) * 8;
    ldsB[it] = (wid * 16 + it * 4) * 256 + lane * 16;  // byte dest (linear)
  }

  // --- fragment read addressing (R4, verified; now as byte offsets) ---
  const int col = lane & 31;
  const int h = lane >> 5;
  int soff[4];
#pragma unroll
  for (int ks = 0; ks < 4; ++ks)
    soff[ks] = ((((col & 1) << 3) + ks * 2 + h) ^ ((col >> 1) & 15)) << 4;
  int aOff[2], bOff[2];
#pragma unroll
  for (int mi = 0; mi < 2; ++mi) aOff[mi] = (wm * 32 + mi * 16 + (col >> 1)) * 256;
#pragma unroll
  for (int ni = 0; ni < 2; ++ni) bOff[ni] = (wn * 32 + ni * 16 + (col >> 1)) * 256;

  f32x16 acc[2][2] = {};
  float4 rAv0[8], rAv1[8];   // A prefetch sets (distance 2)
  uint4v rBv[4];             // B prefetch set (distance 1)

  // --- prologue: B(0), A(0)->set0, A(1)->set1; write buf0; issue B(1), A(2) --
#pragma unroll
  for (int it = 0; it < 4; ++it)
    rBv[it] = *(const uint4v*)(gB + offB[it]);
#pragma unroll
  for (int i = 0; i < 8; ++i)
    rAv0[i] = *(const float4*)(gAr + (size_t)(i * 4) * E_);
#pragma unroll
  for (int i = 0; i < 8; ++i)
    rAv1[i] = *(const float4*)(gAr + (size_t)(i * 4) * E_ + 64);
  {
    uint2 qa[8];
#pragma unroll
    for (int i = 0; i < 8; ++i) {
      qa[i].x = cvt_pk_bf16(rAv0[i].x, rAv0[i].y);
      qa[i].y = cvt_pk_bf16(rAv0[i].z, rAv0[i].w);
    }
#pragma unroll
    for (int i = 0; i < 8; ++i)
      *(uint2*)((char*)As + aWoff[i]) = qa[i];
#pragma unroll
    for (int it = 0; it < 4; ++it)
      *(uint4v*)((char*)Bs + ldsB[it]) = rBv[it];
  }
#pragma unroll
  for (int it = 0; it < 4; ++it)
    rBv[it] = *(const uint4v*)(gB + offB[it] + 64);       // B(1)
#pragma unroll
  for (int i = 0; i < 8; ++i)
    rAv0[i] = *(const float4*)(gAr + (size_t)(i * 4) * E_ + 128);  // A(2)
  asm volatile("s_waitcnt lgkmcnt(0)" ::: "memory");
  __builtin_amdgcn_sched_barrier(0);
  __builtin_amdgcn_s_barrier();
  __builtin_amdgcn_sched_barrier(0);

  // One K-step, single barrier. RD = read-buffer byte offset (0 / 16384).
  // Iter t: pack+write tile t+1 (from RA=rAv{(t+1)&1}, rBv) into RD^16384,
  // issue B((t+2)*64) then A((t+3)*64), compute tile t from RD, barrier.
#define GSTEP(KK, RA, DO_PACK, DO_A, DO_B, RD)                              \
  {                                                                         \
    if (DO_PACK) {                                                          \
      uint2 qa[8];                                                          \
      _Pragma("unroll") for (int i = 0; i < 8; ++i) {                       \
        qa[i].x = cvt_pk_bf16(RA[i].x, RA[i].y);                            \
        qa[i].y = cvt_pk_bf16(RA[i].z, RA[i].w);                            \
      }                                                                     \
      _Pragma("unroll") for (int i = 0; i < 8; ++i)                         \
        *(uint2*)((char*)As + ((RD) ^ 16384) + aWoff[i]) = qa[i];           \
      _Pragma("unroll") for (int it = 0; it < 4; ++it)                      \
        *(uint4v*)((char*)Bs + ((RD) ^ 16384) + ldsB[it]) = rBv[it];        \
    }                                                                       \
    if (DO_B) {                                                             \
      _Pragma("unroll") for (int it = 0; it < 4; ++it)                      \
        rBv[it] = *(const uint4v*)(gB + offB[it] + (KK) + 128);             \
    }                                                                       \
    if (DO_A) {                                                             \
      _Pragma("unroll") for (int i = 0; i < 8; ++i)                         \
        RA[i] = *(const float4*)(gAr + (size_t)(i * 4) * E_ + (KK) + 192);  \
    }                                                                       \
    _Pragma("unroll") for (int ks = 0; ks < 4; ++ks) {                      \
      short8 bf[2], af[2];                                                  \
      _Pragma("unroll") for (int ni = 0; ni < 2; ++ni)                      \
        bf[ni] = *(const short8*)((char*)Bs + (RD) + bOff[ni] + soff[ks]);  \
      _Pragma("unroll") for (int mi = 0; mi < 2; ++mi)                      \
        af[mi] = *(const short8*)((char*)As + (RD) + aOff[mi] + soff[ks]);  \
      _Pragma("unroll") for (int mi = 0; mi < 2; ++mi)                      \
        _Pragma("unroll") for (int ni = 0; ni < 2; ++ni)                    \
          acc[mi][ni] = __builtin_amdgcn_mfma_f32_32x32x16_bf16(            \
              af[mi], bf[ni], acc[mi][ni], 0, 0, 0);                        \
    }                                                                       \
    asm volatile("s_waitcnt lgkmcnt(0)" ::: "memory");                      \
    __builtin_amdgcn_sched_barrier(0);                                      \
    __builtin_amdgcn_s_barrier();                                           \
    __builtin_amdgcn_sched_barrier(0);                                      \
  }

  // main loop: t = 0..27 (14 double-steps), then peeled tail t = 28..31
  for (int kk = 0; kk < 1792; kk += 128) {
    GSTEP(kk, rAv1, 1, 1, 1, 0);
    GSTEP(kk + 64, rAv0, 1, 1, 1, 16384);
  }
  GSTEP(1792, rAv1, 1, 1, 1, 0);      // t=28: pack A29, load B30, A31
  GSTEP(1856, rAv0, 1, 0, 1, 16384);  // t=29: pack A30, load B31
  GSTEP(1920, rAv1, 1, 0, 0, 0);      // t=30: pack A31
  GSTEP(1984, rAv0, 0, 0, 0, 16384);  // t=31: compute only
#undef GSTEP

  // --- epilogue: partial = sum over this wave's 64 n of v[n]*tanh(s+h) ---
  // 32x32 C/D layout (m74/m101): col = lane&31, row = (reg&3)+8*(reg>>2)+4*(lane>>5)
  float vv[2], sv[2];
#pragma unroll
  for (int ni = 0; ni < 2; ++ni) {
    int n = n_base + wn * 64 + ni * 32 + col;
    vv[ni] = vvec[n];
    sv[ni] = sbias[b_idx * D_ + n];
  }
#pragma unroll
  for (int mi = 0; mi < 2; ++mi) {
#pragma unroll
    for (int reg = 0; reg < 16; ++reg) {
      float sum = 0.f;
#pragma unroll
      for (int ni = 0; ni < 2; ++ni)
        sum += vv[ni] * fast_tanh(sv[ni] + acc[mi][ni][reg]);
      sum += __shfl_xor(sum, 1, 64);
      sum += __shfl_xor(sum, 2, 64);
      sum += __shfl_xor(sum, 4, 64);
      sum += __shfl_xor(sum, 8, 64);
      sum += __shfl_xor(sum, 16, 64);
      if (col == 0)
        atomicAdd(&scores[m_base + wm * 64 + mi * 32 + (reg & 3) + 8 * (reg >> 2) + h * 4], sum);
    }
  }
}

// ---------------- kernel 4: softmax over L per b (in-place) -----------------
__global__ __launch_bounds__(256) void k_softmax(float* __restrict__ sc) {
  int b = blockIdx.x, tid = threadIdx.x;
  int lane = tid & 63, wid = tid >> 6;
  float* row = sc + (size_t)b * L_;
  float vals[8];
  float mx = -1e30f;
#pragma unroll
  for (int j = 0; j < 8; ++j) { vals[j] = row[tid + j * 256]; mx = fmaxf(mx, vals[j]); }
#pragma unroll
  for (int off = 32; off >= 1; off >>= 1) mx = fmaxf(mx, __shfl_xor(mx, off, 64));
  __shared__ float redm[4], reds[4];
  if (lane == 0) redm[wid] = mx;
  __syncthreads();
  mx = fmaxf(fmaxf(redm[0], redm[1]), fmaxf(redm[2], redm[3]));
  float sum = 0.f;
#pragma unroll
  for (int j = 0; j < 8; ++j) { vals[j] = __expf(vals[j] - mx); sum += vals[j]; }
#pragma unroll
  for (int off = 32; off >= 1; off >>= 1) sum += __shfl_xor(sum, off, 64);
  if (lane == 0) reds[wid] = sum;
  __syncthreads();
  sum = reds[0] + reds[1] + reds[2] + reds[3];
  float inv = 1.0f / sum;
#pragma unroll
  for (int j = 0; j < 8; ++j) row[tid + j * 256] = vals[j] * inv;
}

// ---------------- kernel 5a: ctx partials (NO atomics) ----------------------
// partial[c][b][e], c = 16 l-chunks of 128 rows. Aliased onto whb (dead after
// k_gemm; k_cvt regenerates it every launch -> replay-safe).
// grid (32, 32): bx -> lc = bx>>1, eh = bx&1; by = b. 1024 blocks, 4/CU.
__global__ __launch_bounds__(256) void k_ctx_p(const float* __restrict__ enc,
                                               const float* __restrict__ attn,
                                               float* __restrict__ partial) {
  int b = blockIdx.y;
  int lc = blockIdx.x >> 1;        // 0..15, 128 rows each
  int eh = blockIdx.x & 1;         // E half
  int t = threadIdx.x;
  __shared__ float aw[128];
  if (t < 128) aw[t] = attn[(size_t)b * L_ + lc * 128 + t];
  __syncthreads();
  const float* base = enc + ((size_t)b * L_ + (size_t)lc * 128) * E_ + eh * 1024;
  float4 a0 = make_float4(0.f, 0.f, 0.f, 0.f);
#pragma unroll 8
  for (int l = 0; l < 128; ++l) {
    float w = aw[l];
    float4 x0 = *(const float4*)(base + (size_t)l * E_ + t * 4);
    a0.x += w * x0.x; a0.y += w * x0.y; a0.z += w * x0.z; a0.w += w * x0.w;
  }
  *(float4*)(partial + ((size_t)(lc * 32 + b) * E_) + eh * 1024 + t * 4) = a0;
}

// ---------------- kernel 5b: reduce partials -> ctx -------------------------
__global__ __launch_bounds__(256) void k_ctx_r(const float* __restrict__ partial,
                                               float* __restrict__ ctx) {
  int idx = blockIdx.x * 256 + threadIdx.x;   // 0..16383
  int b = idx >> 9;                            // 0..31
  int e4 = idx & 511;                          // float4 index within E
  float4 s = make_float4(0.f, 0.f, 0.f, 0.f);
#pragma unroll
  for (int c = 0; c < 16; ++c) {
    float4 p = *(const float4*)(partial + ((size_t)(c * 32 + b) * E_) + e4 * 4);
    s.x += p.x; s.y += p.y; s.z += p.z; s.w += p.w;
  }
  *(float4*)(ctx + (size_t)b * E_ + e4 * 4) = s;
}

extern "C" void kernel_launch(void* const* d_in, const int* in_sizes, int n_in,
                              void* d_out, int out_size, void* d_ws, size_t ws_size,
                              hipStream_t stream) {
  const float* dec = (const float*)d_in[0];  // [32,1024]
  const float* enc = (const float*)d_in[1];  // [32,2048,2048]
  const float* Ws  = (const float*)d_in[2];  // [1024,1024]
  const float* Wh  = (const float*)d_in[3];  // [1024,2048]
  const float* v   = (const float*)d_in[4];  // [1024]

  float* ctx  = (float*)d_out;                   // [32,2048]
  float* attn = (float*)d_out + B_ * E_;         // [32,2048]; also scores scratch

  // workspace: W_h bf16 (4 MB; reused as ctx partials after k_gemm) + s (128KB)
  unsigned short* whb = (unsigned short*)d_ws;
  float* partial = (float*)d_ws;                 // alias, 16*32*2048 f32 = 4 MB
  float* sbuf = (float*)((char*)d_ws + (size_t)D_ * E_ * sizeof(unsigned short));

  // zero scores (accumulated via atomics); ctx is plain-stored by k_ctx_r
  hipMemsetAsync(d_out, 0, (size_t)out_size * sizeof(float), stream);

  k_s<<<dim3((B_ * D_) / 4), dim3(256), 0, stream>>>(dec, Ws, sbuf);
  k_cvt<<<dim3((D_ * E_) / (256 * 8)), dim3(256), 0, stream>>>(Wh, whb);
  k_gemm<<<dim3((B_ * L_ / 128) * (D_ / 128)), dim3(256), 0, stream>>>(enc, whb, sbuf, v, attn);
  k_softmax<<<dim3(B_), dim3(256), 0, stream>>>(attn);
  k_ctx_p<<<dim3(32, B_), dim3(256), 0, stream>>>(enc, attn, partial);
  k_ctx_r<<<dim3((B_ * E_) / (256 * 4)), dim3(256), 0, stream>>>(partial, ctx);
}